// Round 12
// baseline (557.358 us; speedup 1.0000x reference)
//
#include <hip/hip_runtime.h>

typedef unsigned short u16;
typedef unsigned int u32;

#define NN 8192
#define CAP 128

typedef __attribute__((ext_vector_type(8))) short short8;
typedef __attribute__((ext_vector_type(4))) float floatx4;

__device__ __forceinline__ u16 f2bf(float f) {
    union { float f; u32 i; } w;
    w.f = f;
    u32 i = w.i;
    u32 r = (i + 0x7FFFu + ((i >> 16) & 1u)) >> 16;
    return (u16)r;
}
__device__ __forceinline__ float lo_bf(u32 v) {
    union { u32 i; float f; } w;
    w.i = v << 16;
    return w.f;
}
__device__ __forceinline__ float hi_bf(u32 v) {
    union { u32 i; float f; } w;
    w.i = v & 0xFFFF0000u;
    return w.f;
}
__device__ __forceinline__ float softplusf(float x) {
    return fmaxf(x, 0.0f) + log1pf(expf(-fabsf(x)));
}

// ---------------- wave-per-row pass over f32 adjacency ----------------
// Symmetric matrix => deg_in == deg_out; one degree/norm array serves both.
__global__ __launch_bounds__(256) void build_graph(
    const float* __restrict__ adj, int* __restrict__ deg,
    float* __restrict__ snorm, u32* __restrict__ edges)
{
    const int wave = threadIdx.x >> 6, lane = threadIdx.x & 63;
    const int i = blockIdx.x * 4 + wave;
    __shared__ int cnt[4];
    if (threadIdx.x < 4) cnt[threadIdx.x] = 0;
    __syncthreads();
    const uint4* rowp = (const uint4*)(adj + (size_t)i * NN);
    u32* erow = edges + (size_t)i * CAP;
#pragma unroll 4
    for (int it = 0; it < 32; ++it) {            // 32 * 64 lanes * 4 f32 = 8192
        uint4 v = rowp[it * 64 + lane];
        int jb = (it * 64 + lane) * 4;
        u32 w[4] = { v.x, v.y, v.z, v.w };
#pragma unroll
        for (int e = 0; e < 4; ++e) {
            int j = jb + e;
            if ((i != j) && ((w[e] & 0x7FFFFFFFu) != 0)) {
                int slot = atomicAdd(&cnt[wave], 1);   // LDS atomic, wave-local
                if (slot < CAP) erow[slot] = (u32)j;
            }
        }
    }
    __syncthreads();
    if (lane == 0) {
        int c = cnt[wave];
        deg[i] = c;
        snorm[i] = rsqrtf((float)max(c, 1));
    }
}

// ---------------- concat [emb|pos] (f32), pre-scaled by snorm -> bf16 [8192x128] ----------------
__global__ void concat_feat(const float* __restrict__ emb, const float* __restrict__ pos,
                            const float* __restrict__ snorm, u16* __restrict__ out) {
    int idx = blockIdx.x * 256 + threadIdx.x;   // 8192*128 total
    int i = idx >> 7, f = idx & 127;
    float v = (f < 125) ? emb[i * 125 + f] : pos[i * 3 + (f - 125)];
    out[idx] = f2bf(v * snorm[i]);
}

// ---------------- all 4 weight transposes in one launch ----------------
__global__ void transpose_all(const float* __restrict__ W0, const float* __restrict__ W1,
                              const float* __restrict__ W2, const float* __restrict__ W3,
                              u16* __restrict__ T0, u16* __restrict__ T1,
                              u16* __restrict__ T2, u16* __restrict__ T3) {
    __shared__ float tile[32][33];
    const int z = blockIdx.z;
    const float* W = (z == 0) ? W0 : (z == 1) ? W1 : (z == 2) ? W2 : W3;
    u16* WT       = (z == 0) ? T0 : (z == 1) ? T1 : (z == 2) ? T2 : T3;
    const int K = (z == 0) ? 128 : 512;
    const int N = 512;
    int bx = blockIdx.x * 32;   // n
    int by = blockIdx.y * 32;   // k
    if (by >= K) return;
    int tx = threadIdx.x & 31, ty = threadIdx.x >> 5;  // 256 threads
#pragma unroll
    for (int yy = ty; yy < 32; yy += 8)
        tile[yy][tx] = W[(size_t)(by + yy) * N + bx + tx];
    __syncthreads();
#pragma unroll
    for (int yy = ty; yy < 32; yy += 8)
        WT[(size_t)(bx + yy) * K + by + tx] = f2bf(tile[tx][yy]);
}

// ---------------- SpMM F=512, COLUMN-HALF pass ----------------
// Two dispatches per layer, each gathering a 4MB column half of feat ->
// working set fits EVERY XCD's 4MB L2 (read-only replication) -> ~full L2 hits
// (single-pass 8MB working set gave ~50% L2 / 50% LLC at ~13 TB/s).
// 64 lanes x uint2 (4 bf16) = 256 cols; row stride 128 uint2; colOff in {0,64}.
__global__ __launch_bounds__(256) void spmm_half(
    const u32* __restrict__ edges, const int* __restrict__ deg,
    const float* __restrict__ snorm,
    const uint2* __restrict__ feat2, uint2* __restrict__ out2, int colOff)
{
    __shared__ int sh_i[4][CAP];
    const int wave = threadIdx.x >> 6, lane = threadIdx.x & 63;
    const int j = blockIdx.x * 4 + wave;
    const int cnt = min(deg[j], CAP);
    for (int c = lane; c < cnt; c += 64)
        sh_i[wave][c] = (int)edges[(size_t)j * CAP + c];
    __syncthreads();
    float a[4] = {};
#pragma unroll 4
    for (int c = 0; c < cnt; ++c) {
        uint2 v = feat2[(size_t)sh_i[wave][c] * 128 + colOff + lane];
        a[0] += lo_bf(v.x); a[1] += hi_bf(v.x);
        a[2] += lo_bf(v.y); a[3] += hi_bf(v.y);
    }
    float sj = snorm[j];
    uint2 o;
    o.x = (u32)f2bf(a[0] * sj) | ((u32)f2bf(a[1] * sj) << 16);
    o.y = (u32)f2bf(a[2] * sj) | ((u32)f2bf(a[3] * sj) << 16);
    out2[(size_t)j * 128 + colOff + lane] = o;
}

// ---------------- SpMM F=128 (layer 0): u32 loads, all 64 lanes active ----------------
__global__ __launch_bounds__(256) void spmm128(
    const u32* __restrict__ edges, const int* __restrict__ deg,
    const float* __restrict__ snorm,
    const u32* __restrict__ feat1, u32* __restrict__ out1)
{
    __shared__ int sh_i[4][CAP];
    const int wave = threadIdx.x >> 6, lane = threadIdx.x & 63;
    const int j = blockIdx.x * 4 + wave;
    const int cnt = min(deg[j], CAP);
    for (int c = lane; c < cnt; c += 64)
        sh_i[wave][c] = (int)edges[(size_t)j * CAP + c];
    __syncthreads();
    float a0 = 0.f, a1 = 0.f;
#pragma unroll 4
    for (int c = 0; c < cnt; ++c) {
        u32 v = feat1[(size_t)sh_i[wave][c] * 64 + lane];   // 128 cols = 64 u32
        a0 += lo_bf(v); a1 += hi_bf(v);
    }
    float sj = snorm[j];
    out1[(size_t)j * 64 + lane] = (u32)f2bf(a0 * sj) | ((u32)f2bf(a1 * sj) << 16);
}

// ---------------- GEMM: out = softplus(A[M,K] @ W + b) [* snorm[row] inner layers] ----------------
// BM=64, BN=64, BK=64 -> 1024 blocks = 4/CU; XOR-swizzled LDS (conflict-free,
// R10->R11: SQ_LDS_BANK_CONFLICT 3.8e7 -> ~0); async global_load_lds staging.
__global__ __launch_bounds__(256, 4) void gemm_bias_softplus(
    const u16* __restrict__ A, const u16* __restrict__ BT,
    const float* __restrict__ bias, const float* __restrict__ snorm,
    float* __restrict__ outf, u16* __restrict__ outb,
    int M, int N, int K)
{
    __shared__ u16 lA[64 * 64];    // [row][k] 8KB, swizzled slots
    __shared__ u16 lB[64 * 64];    // [col][k] 8KB, swizzled slots
    const int tid = threadIdx.x;
    const int wave = tid >> 6;
    const int lane = tid & 63;
    const int q = lane >> 4;
    const int m16 = lane & 15;
    const int wm = (wave >> 1) * 32;
    const int wn = (wave & 1) * 32;
    const int bm = blockIdx.x, bn = blockIdx.y;

    const int r32 = tid >> 3;             // 0..31 staging row within half
    const int cb  = tid & 7;              // LDS slot index 0..7
    const int cg  = cb ^ (r32 & 7);       // swizzled global col block
    const u16* gA0 = A  + (size_t)(bm * 64 + r32) * K + cg * 8;
    const u16* gA1 = A  + (size_t)(bm * 64 + 32 + r32) * K + cg * 8;
    const u16* gB0 = BT + (size_t)(bn * 64 + r32) * K + cg * 8;
    const u16* gB1 = BT + (size_t)(bn * 64 + 32 + r32) * K + cg * 8;
    u16* lAp0 = lA + tid * 8;
    u16* lAp1 = lA + 2048 + tid * 8;
    u16* lBp0 = lB + tid * 8;
    u16* lBp1 = lB + 2048 + tid * 8;

    floatx4 acc[2][2] = {};

    for (int k0 = 0; k0 < K; k0 += 64) {
        __builtin_amdgcn_global_load_lds(
            (const __attribute__((address_space(1))) u32*)(const void*)(gA0 + k0),
            (__attribute__((address_space(3))) u32*)(void*)lAp0, 16, 0, 0);
        __builtin_amdgcn_global_load_lds(
            (const __attribute__((address_space(1))) u32*)(const void*)(gA1 + k0),
            (__attribute__((address_space(3))) u32*)(void*)lAp1, 16, 0, 0);
        __builtin_amdgcn_global_load_lds(
            (const __attribute__((address_space(1))) u32*)(const void*)(gB0 + k0),
            (__attribute__((address_space(3))) u32*)(void*)lBp0, 16, 0, 0);
        __builtin_amdgcn_global_load_lds(
            (const __attribute__((address_space(1))) u32*)(const void*)(gB1 + k0),
            (__attribute__((address_space(3))) u32*)(void*)lBp1, 16, 0, 0);
        __syncthreads();   // barrier semantics drain vmcnt first

        short8 af[2][2], bfr[2][2];
#pragma unroll
        for (int im = 0; im < 2; ++im) {
            int row = wm + im * 16 + m16;
#pragma unroll
            for (int kk = 0; kk < 2; ++kk) {
                int slot = (kk * 4 + q) ^ (m16 & 7);
                af[im][kk] = *(const short8*)&lA[row * 64 + slot * 8];
            }
        }
#pragma unroll
        for (int in = 0; in < 2; ++in) {
            int row = wn + in * 16 + m16;
#pragma unroll
            for (int kk = 0; kk < 2; ++kk) {
                int slot = (kk * 4 + q) ^ (m16 & 7);
                bfr[in][kk] = *(const short8*)&lB[row * 64 + slot * 8];
            }
        }
#pragma unroll
        for (int kk = 0; kk < 2; ++kk)
#pragma unroll
            for (int im = 0; im < 2; ++im)
#pragma unroll
                for (int in = 0; in < 2; ++in)
                    acc[im][in] = __builtin_amdgcn_mfma_f32_16x16x32_bf16(
                        af[im][kk], bfr[in][kk], acc[im][in], 0, 0, 0);
        __syncthreads();
    }

    // epilogue: C/D layout col = lane&15, row = q*4 + reg  [measured m89/m91]
#pragma unroll
    for (int im = 0; im < 2; ++im) {
#pragma unroll
        for (int in = 0; in < 2; ++in) {
            int col = bn * 64 + wn + in * 16 + m16;
            float bvf = bias[col];
#pragma unroll
            for (int r = 0; r < 4; ++r) {
                int row = bm * 64 + wm + im * 16 + q * 4 + r;
                float v = softplusf(acc[im][in][r] + bvf);
                if (outf) outf[(size_t)row * N + col] = v;
                else      outb[(size_t)row * N + col] = f2bf(v * snorm[row]);
            }
        }
    }
}

extern "C" void kernel_launch(void* const* d_in, const int* in_sizes, int n_in,
                              void* d_out, int out_size, void* d_ws, size_t ws_size,
                              hipStream_t stream)
{
    const float* atom_pos = (const float*)d_in[0];
    const float* dist_adj = (const float*)d_in[1];
    const float* atom_emb = (const float*)d_in[2];
    const float* Wm[4] = { (const float*)d_in[3], (const float*)d_in[5],
                           (const float*)d_in[7], (const float*)d_in[9] };
    const float* bv[4] = { (const float*)d_in[4], (const float*)d_in[6],
                           (const float*)d_in[8], (const float*)d_in[10] };

    char* p = (char*)d_ws;
    auto alloc = [&](size_t n) { char* r = p; p += (n + 255) & ~(size_t)255; return r; };
    int*   deg   = (int*)alloc(NN * 4);
    float* snorm = (float*)alloc(NN * 4);
    u32*   edges = (u32*)alloc((size_t)NN * CAP * 4);
    u16*   wt[4];
    wt[0] = (u16*)alloc(512 * 128 * 2);
    wt[1] = (u16*)alloc(512 * 512 * 2);
    wt[2] = (u16*)alloc(512 * 512 * 2);
    wt[3] = (u16*)alloc(512 * 512 * 2);
    u16* buf0 = (u16*)alloc((size_t)NN * 512 * 2);
    u16* buf1 = (u16*)alloc((size_t)NN * 512 * 2);

    build_graph<<<NN / 4, 256, 0, stream>>>(dist_adj, deg, snorm, edges);
    concat_feat<<<(NN * 128) / 256, 256, 0, stream>>>(atom_emb, atom_pos, snorm, buf0);
    transpose_all<<<dim3(16, 16, 4), 256, 0, stream>>>(
        Wm[0], Wm[1], Wm[2], Wm[3], wt[0], wt[1], wt[2], wt[3]);

    const u16* feat = buf0;
    int F = 128;
    for (int l = 0; l < 4; ++l) {
        if (F == 128) {
            spmm128<<<NN / 4, 256, 0, stream>>>(edges, deg, snorm,
                                                (const u32*)feat, (u32*)buf1);
        } else {
            spmm_half<<<NN / 4, 256, 0, stream>>>(edges, deg, snorm,
                                                  (const uint2*)feat, (uint2*)buf1, 0);
            spmm_half<<<NN / 4, 256, 0, stream>>>(edges, deg, snorm,
                                                  (const uint2*)feat, (uint2*)buf1, 64);
        }
        float* outf = (l == 3) ? (float*)d_out : nullptr;
        u16*   outb = (l == 3) ? nullptr : buf0;
        gemm_bias_softplus<<<dim3(NN / 64, 512 / 64), 256, 0, stream>>>(
            buf1, wt[l], bv[l], snorm, outf, outb, NN, 512, F);
        feat = buf0;
        F = 512;
    }
}

// Round 13
// 543.741 us; speedup vs baseline: 1.0250x; 1.0250x over previous
//
#include <hip/hip_runtime.h>

typedef unsigned short u16;
typedef unsigned int u32;

#define NN 8192
#define CAP 128

typedef __attribute__((ext_vector_type(8))) short short8;
typedef __attribute__((ext_vector_type(4))) float floatx4;

__device__ __forceinline__ u16 f2bf(float f) {
    union { float f; u32 i; } w;
    w.f = f;
    u32 i = w.i;
    u32 r = (i + 0x7FFFu + ((i >> 16) & 1u)) >> 16;
    return (u16)r;
}
__device__ __forceinline__ float lo_bf(u32 v) {
    union { u32 i; float f; } w;
    w.i = v << 16;
    return w.f;
}
__device__ __forceinline__ float hi_bf(u32 v) {
    union { u32 i; float f; } w;
    w.i = v & 0xFFFF0000u;
    return w.f;
}
__device__ __forceinline__ float softplusf(float x) {
    return fmaxf(x, 0.0f) + log1pf(expf(-fabsf(x)));
}

// ---------------- PROLOGUE MEGA-KERNEL ----------------
// Blocks 0..2047:   build_graph (wave-per-row edge list + degree + rsqrt norm)
//                   then concat+scale the same 4 rows' features (no cross-block dep).
// Blocks 2048..3071: 32x32 weight transposes f32->bf16 (independent; ride along
//                   ~free under the HBM-bound adjacency stream).
__global__ __launch_bounds__(256) void prologue(
    const float* __restrict__ adj,
    const float* __restrict__ emb, const float* __restrict__ pos,
    const float* __restrict__ W0, const float* __restrict__ W1,
    const float* __restrict__ W2, const float* __restrict__ W3,
    u16* __restrict__ T0, u16* __restrict__ T1,
    u16* __restrict__ T2, u16* __restrict__ T3,
    int* __restrict__ deg, float* __restrict__ snorm,
    u32* __restrict__ edges, u16* __restrict__ feat0)
{
    __shared__ char shraw[32 * 33 * 4];   // union: cnt[4] (build) | tile[32][33] (transpose)
    const int b = blockIdx.x;

    if (b < 2048) {
        // ---- build_graph + fused concat ----
        int* cnt = (int*)shraw;
        const int wave = threadIdx.x >> 6, lane = threadIdx.x & 63;
        const int i = b * 4 + wave;
        if (threadIdx.x < 4) cnt[threadIdx.x] = 0;
        __syncthreads();
        const uint4* rowp = (const uint4*)(adj + (size_t)i * NN);
        u32* erow = edges + (size_t)i * CAP;
#pragma unroll 4
        for (int it = 0; it < 32; ++it) {            // 32 * 64 lanes * 4 f32 = 8192
            uint4 v = rowp[it * 64 + lane];
            int jb = (it * 64 + lane) * 4;
            u32 w[4] = { v.x, v.y, v.z, v.w };
#pragma unroll
            for (int e = 0; e < 4; ++e) {
                int j = jb + e;
                if ((i != j) && ((w[e] & 0x7FFFFFFFu) != 0)) {
                    int slot = atomicAdd(&cnt[wave], 1);   // LDS atomic, wave-local
                    if (slot < CAP) erow[slot] = (u32)j;
                }
            }
        }
        __syncthreads();
        int c = cnt[wave];
        float s = rsqrtf((float)max(c, 1));
        if (lane == 0) { deg[i] = c; snorm[i] = s; }
        // concat [emb|pos] row i, pre-scaled by s -> bf16 (2 cols per lane)
#pragma unroll
        for (int h = 0; h < 2; ++h) {
            int f = lane + h * 64;
            float v = (f < 125) ? emb[(size_t)i * 125 + f] : pos[(size_t)i * 3 + (f - 125)];
            feat0[(size_t)i * 128 + f] = f2bf(v * s);
        }
    } else {
        // ---- weight transposes ----
        float (*tile)[33] = (float(*)[33])shraw;
        int b2 = b - 2048;
        int z = b2 >> 8, rem = b2 & 255;
        const float* W = (z == 0) ? W0 : (z == 1) ? W1 : (z == 2) ? W2 : W3;
        u16* WT       = (z == 0) ? T0 : (z == 1) ? T1 : (z == 2) ? T2 : T3;
        const int K = (z == 0) ? 128 : 512;
        const int N = 512;
        int bx = (rem & 15) * 32;   // n
        int by = (rem >> 4) * 32;   // k
        if (by >= K) return;        // block-uniform
        int tx = threadIdx.x & 31, ty = threadIdx.x >> 5;
#pragma unroll
        for (int yy = ty; yy < 32; yy += 8)
            tile[yy][tx] = W[(size_t)(by + yy) * N + bx + tx];
        __syncthreads();
#pragma unroll
        for (int yy = ty; yy < 32; yy += 8)
            WT[(size_t)(bx + yy) * K + by + tx] = f2bf(tile[tx][yy]);
    }
}

// ---------------- SpMM F=512: out[j,:] = snorm[j] * sum_{i in N(j)} featS[i,:] ----------------
// featS PRE-SCALED by snorm[src]; single-pass uint4 (full 1KB row per wave-load).
__global__ __launch_bounds__(256) void spmm512(
    const u32* __restrict__ edges, const int* __restrict__ deg,
    const float* __restrict__ snorm,
    const uint4* __restrict__ feat4, uint4* __restrict__ out4)
{
    __shared__ int sh_i[4][CAP];
    const int wave = threadIdx.x >> 6, lane = threadIdx.x & 63;
    const int j = blockIdx.x * 4 + wave;
    const int cnt = min(deg[j], CAP);
    for (int c = lane; c < cnt; c += 64)
        sh_i[wave][c] = (int)edges[(size_t)j * CAP + c];
    __syncthreads();
    float a[8] = {};
#pragma unroll 4
    for (int c = 0; c < cnt; ++c) {
        uint4 v = feat4[(size_t)sh_i[wave][c] * 64 + lane];   // 512 cols = 64 uint4
        a[0] += lo_bf(v.x); a[1] += hi_bf(v.x);
        a[2] += lo_bf(v.y); a[3] += hi_bf(v.y);
        a[4] += lo_bf(v.z); a[5] += hi_bf(v.z);
        a[6] += lo_bf(v.w); a[7] += hi_bf(v.w);
    }
    float sj = snorm[j];
    uint4 o;
    o.x = (u32)f2bf(a[0] * sj) | ((u32)f2bf(a[1] * sj) << 16);
    o.y = (u32)f2bf(a[2] * sj) | ((u32)f2bf(a[3] * sj) << 16);
    o.z = (u32)f2bf(a[4] * sj) | ((u32)f2bf(a[5] * sj) << 16);
    o.w = (u32)f2bf(a[6] * sj) | ((u32)f2bf(a[7] * sj) << 16);
    out4[(size_t)j * 64 + lane] = o;
}

// ---------------- SpMM F=128 (layer 0): u32 loads, all 64 lanes active ----------------
__global__ __launch_bounds__(256) void spmm128(
    const u32* __restrict__ edges, const int* __restrict__ deg,
    const float* __restrict__ snorm,
    const u32* __restrict__ feat1, u32* __restrict__ out1)
{
    __shared__ int sh_i[4][CAP];
    const int wave = threadIdx.x >> 6, lane = threadIdx.x & 63;
    const int j = blockIdx.x * 4 + wave;
    const int cnt = min(deg[j], CAP);
    for (int c = lane; c < cnt; c += 64)
        sh_i[wave][c] = (int)edges[(size_t)j * CAP + c];
    __syncthreads();
    float a0 = 0.f, a1 = 0.f;
#pragma unroll 4
    for (int c = 0; c < cnt; ++c) {
        u32 v = feat1[(size_t)sh_i[wave][c] * 64 + lane];   // 128 cols = 64 u32
        a0 += lo_bf(v); a1 += hi_bf(v);
    }
    float sj = snorm[j];
    out1[(size_t)j * 64 + lane] = (u32)f2bf(a0 * sj) | ((u32)f2bf(a1 * sj) << 16);
}

// ---------------- GEMM: out = softplus(A[M,K] @ W + b) [* snorm[row] inner layers] ----------------
// BM=64, BN=64, BK=64 -> 1024 blocks = 4/CU; XOR-swizzled LDS (conflict-free,
// R10->R11: SQ_LDS_BANK_CONFLICT 3.8e7 -> ~0); async global_load_lds staging.
__global__ __launch_bounds__(256, 4) void gemm_bias_softplus(
    const u16* __restrict__ A, const u16* __restrict__ BT,
    const float* __restrict__ bias, const float* __restrict__ snorm,
    float* __restrict__ outf, u16* __restrict__ outb,
    int M, int N, int K)
{
    __shared__ u16 lA[64 * 64];    // [row][k] 8KB, swizzled slots
    __shared__ u16 lB[64 * 64];    // [col][k] 8KB, swizzled slots
    const int tid = threadIdx.x;
    const int wave = tid >> 6;
    const int lane = tid & 63;
    const int q = lane >> 4;
    const int m16 = lane & 15;
    const int wm = (wave >> 1) * 32;
    const int wn = (wave & 1) * 32;
    const int bm = blockIdx.x, bn = blockIdx.y;

    const int r32 = tid >> 3;             // 0..31 staging row within half
    const int cb  = tid & 7;              // LDS slot index 0..7
    const int cg  = cb ^ (r32 & 7);       // swizzled global col block
    const u16* gA0 = A  + (size_t)(bm * 64 + r32) * K + cg * 8;
    const u16* gA1 = A  + (size_t)(bm * 64 + 32 + r32) * K + cg * 8;
    const u16* gB0 = BT + (size_t)(bn * 64 + r32) * K + cg * 8;
    const u16* gB1 = BT + (size_t)(bn * 64 + 32 + r32) * K + cg * 8;
    u16* lAp0 = lA + tid * 8;
    u16* lAp1 = lA + 2048 + tid * 8;
    u16* lBp0 = lB + tid * 8;
    u16* lBp1 = lB + 2048 + tid * 8;

    floatx4 acc[2][2] = {};

    for (int k0 = 0; k0 < K; k0 += 64) {
        __builtin_amdgcn_global_load_lds(
            (const __attribute__((address_space(1))) u32*)(const void*)(gA0 + k0),
            (__attribute__((address_space(3))) u32*)(void*)lAp0, 16, 0, 0);
        __builtin_amdgcn_global_load_lds(
            (const __attribute__((address_space(1))) u32*)(const void*)(gA1 + k0),
            (__attribute__((address_space(3))) u32*)(void*)lAp1, 16, 0, 0);
        __builtin_amdgcn_global_load_lds(
            (const __attribute__((address_space(1))) u32*)(const void*)(gB0 + k0),
            (__attribute__((address_space(3))) u32*)(void*)lBp0, 16, 0, 0);
        __builtin_amdgcn_global_load_lds(
            (const __attribute__((address_space(1))) u32*)(const void*)(gB1 + k0),
            (__attribute__((address_space(3))) u32*)(void*)lBp1, 16, 0, 0);
        __syncthreads();   // barrier semantics drain vmcnt first

        short8 af[2][2], bfr[2][2];
#pragma unroll
        for (int im = 0; im < 2; ++im) {
            int row = wm + im * 16 + m16;
#pragma unroll
            for (int kk = 0; kk < 2; ++kk) {
                int slot = (kk * 4 + q) ^ (m16 & 7);
                af[im][kk] = *(const short8*)&lA[row * 64 + slot * 8];
            }
        }
#pragma unroll
        for (int in = 0; in < 2; ++in) {
            int row = wn + in * 16 + m16;
#pragma unroll
            for (int kk = 0; kk < 2; ++kk) {
                int slot = (kk * 4 + q) ^ (m16 & 7);
                bfr[in][kk] = *(const short8*)&lB[row * 64 + slot * 8];
            }
        }
#pragma unroll
        for (int kk = 0; kk < 2; ++kk)
#pragma unroll
            for (int im = 0; im < 2; ++im)
#pragma unroll
                for (int in = 0; in < 2; ++in)
                    acc[im][in] = __builtin_amdgcn_mfma_f32_16x16x32_bf16(
                        af[im][kk], bfr[in][kk], acc[im][in], 0, 0, 0);
        __syncthreads();
    }

    // epilogue: C/D layout col = lane&15, row = q*4 + reg  [measured m89/m91]
#pragma unroll
    for (int im = 0; im < 2; ++im) {
#pragma unroll
        for (int in = 0; in < 2; ++in) {
            int col = bn * 64 + wn + in * 16 + m16;
            float bvf = bias[col];
#pragma unroll
            for (int r = 0; r < 4; ++r) {
                int row = bm * 64 + wm + im * 16 + q * 4 + r;
                float v = softplusf(acc[im][in][r] + bvf);
                if (outf) outf[(size_t)row * N + col] = v;
                else      outb[(size_t)row * N + col] = f2bf(v * snorm[row]);
            }
        }
    }
}

extern "C" void kernel_launch(void* const* d_in, const int* in_sizes, int n_in,
                              void* d_out, int out_size, void* d_ws, size_t ws_size,
                              hipStream_t stream)
{
    const float* atom_pos = (const float*)d_in[0];
    const float* dist_adj = (const float*)d_in[1];
    const float* atom_emb = (const float*)d_in[2];
    const float* Wm[4] = { (const float*)d_in[3], (const float*)d_in[5],
                           (const float*)d_in[7], (const float*)d_in[9] };
    const float* bv[4] = { (const float*)d_in[4], (const float*)d_in[6],
                           (const float*)d_in[8], (const float*)d_in[10] };

    char* p = (char*)d_ws;
    auto alloc = [&](size_t n) { char* r = p; p += (n + 255) & ~(size_t)255; return r; };
    int*   deg   = (int*)alloc(NN * 4);
    float* snorm = (float*)alloc(NN * 4);
    u32*   edges = (u32*)alloc((size_t)NN * CAP * 4);
    u16*   wt[4];
    wt[0] = (u16*)alloc(512 * 128 * 2);
    wt[1] = (u16*)alloc(512 * 512 * 2);
    wt[2] = (u16*)alloc(512 * 512 * 2);
    wt[3] = (u16*)alloc(512 * 512 * 2);
    u16* buf0 = (u16*)alloc((size_t)NN * 512 * 2);
    u16* buf1 = (u16*)alloc((size_t)NN * 512 * 2);

    prologue<<<2048 + 1024, 256, 0, stream>>>(
        dist_adj, atom_emb, atom_pos,
        Wm[0], Wm[1], Wm[2], Wm[3], wt[0], wt[1], wt[2], wt[3],
        deg, snorm, edges, buf0);

    const u16* feat = buf0;
    int F = 128;
    for (int l = 0; l < 4; ++l) {
        if (F == 128)
            spmm128<<<NN / 4, 256, 0, stream>>>(edges, deg, snorm,
                                                (const u32*)feat, (u32*)buf1);
        else
            spmm512<<<NN / 4, 256, 0, stream>>>(edges, deg, snorm,
                                                (const uint4*)feat, (uint4*)buf1);
        float* outf = (l == 3) ? (float*)d_out : nullptr;
        u16*   outb = (l == 3) ? nullptr : buf0;
        gemm_bias_softplus<<<dim3(NN / 64, 512 / 64), 256, 0, stream>>>(
            buf1, wt[l], bv[l], snorm, outf, outb, NN, 512, F);
        feat = buf0;
        F = 512;
    }
}